// Round 1
// baseline (8311.951 us; speedup 1.0000x reference)
//
#include <hip/hip_runtime.h>
#include <hip/hip_bf16.h>

// LocalCrossAttentionBlock3D — R0 f32 baseline.
// B=2, C=96, D=H=W=48, NH=4, dh=24, WIN=2^3, HID=384.
// Tokens: window-major g = n*8+l, n = ((b*24+dw)*24+hw)*24+ww, l = ld*4+lh*2+lw.
// G = 221184 tokens per stream.

#define G_TOK 221184          // 2*110592
#define TOK_PER_B 110592
#define STREAM_ELEMS 21233664 // G_TOK*96

__device__ __forceinline__ float gelu_f(float x) {
    return 0.5f * x * (1.0f + erff(x * 0.70710678118654752f));
}

// ---------------------------------------------------------------------------
// K0: fold LN affines (and attention scale) into projection weights.
// wp layout (floats): WQ'[96*96] @0, WK' @9216, WV' @18432, W1' [384*96] @27648,
//                     bq' @64512, bk' @64608, bv' @64704, b1' @64800 (384)
__global__ __launch_bounds__(256) void k_fold(
    const float* __restrict__ Wi, const float* __restrict__ bi,
    const float* __restrict__ W1, const float* __restrict__ b1,
    const float* __restrict__ qnw, const float* __restrict__ qnb,
    const float* __restrict__ kvnw, const float* __restrict__ kvnb,
    const float* __restrict__ ffnw, const float* __restrict__ ffnb,
    float* __restrict__ wp)
{
    const float scale = 0.20412414523193150f; // 1/sqrt(24)
    int tid = threadIdx.x;
    for (int i = tid; i < 96 * 96; i += 256) {
        int c = i / 96, k = i % 96;
        wp[i]         = Wi[c * 96 + k] * qnw[k] * scale;
        wp[9216 + i]  = Wi[(96 + c) * 96 + k] * kvnw[k];
        wp[18432 + i] = Wi[(192 + c) * 96 + k] * kvnw[k];
    }
    for (int i = tid; i < 384 * 96; i += 256) {
        int k = i % 96;
        wp[27648 + i] = W1[i] * ffnw[k];
    }
    for (int c = tid; c < 96; c += 256) {
        float s0 = bi[c], s1 = bi[96 + c], s2 = bi[192 + c];
        for (int k = 0; k < 96; ++k) {
            s0 += qnb[k] * Wi[c * 96 + k];
            s1 += kvnb[k] * Wi[(96 + c) * 96 + k];
            s2 += kvnb[k] * Wi[(192 + c) * 96 + k];
        }
        wp[64512 + c] = s0 * scale;
        wp[64608 + c] = s1;
        wp[64704 + c] = s2;
    }
    for (int c = tid; c < 384; c += 256) {
        float s = b1[c];
        for (int k = 0; k < 96; ++k) s += ffnb[k] * W1[c * 96 + k];
        wp[64800 + c] = s;
    }
}

// ---------------------------------------------------------------------------
// K1: gather [B,C,D,H,W] -> token-major X[G,96]; per-token LN stats (mean, rstd).
// grid: 2 streams * 1152 (b,dw,hw); block 256.
__global__ __launch_bounds__(256) void k_gather(
    const float* __restrict__ srcf, const float* __restrict__ srcb,
    float* __restrict__ Xf, float* __restrict__ Xb,
    float* __restrict__ Mf, float* __restrict__ Rf,
    float* __restrict__ Mb, float* __restrict__ Rb)
{
    __shared__ float tile[192 * 97];
    int blk = blockIdx.x;
    const float* src; float* X; float* M; float* R;
    if (blk < 1152) { src = srcf; X = Xf; M = Mf; R = Rf; }
    else            { src = srcb; X = Xb; M = Mb; R = Rb; blk -= 1152; }
    int b = blk / 576, rem = blk % 576, dw = rem / 24, hw = rem % 24;
    int tid = threadIdx.x;
    for (int i = tid; i < 384 * 48; i += 256) {
        int r = i / 48, w = i % 48;
        int c = r >> 2, d_off = (r >> 1) & 1, h_off = r & 1;
        float v = src[((((long)b * 96 + c) * 48 + dw * 2 + d_off) * 48 + hw * 2 + h_off) * 48 + w];
        int t = (w >> 1) * 8 + d_off * 4 + h_off * 2 + (w & 1);
        tile[t * 97 + c] = v;
    }
    __syncthreads();
    long base = ((((long)b * 24 + dw) * 24 + hw) * 24) * 8;
    if (tid < 192) {
        float s = 0.f, ss = 0.f;
        for (int c = 0; c < 96; ++c) { float v = tile[tid * 97 + c]; s += v; ss += v * v; }
        float m = s * (1.f / 96.f);
        float var = ss * (1.f / 96.f) - m * m;
        M[base + tid] = m;
        R[base + tid] = rsqrtf(var + 1e-5f);
    }
    for (int i = tid; i < 192 * 96; i += 256) {
        int t = i / 96, c = i % 96;
        X[(base + t) * 96 + c] = tile[t * 97 + c];
    }
}

// ---------------------------------------------------------------------------
// 32-row x 96-col GEMM from LDS src (stride 100) with global/ws weights [96][96].
// Row cached in regs; weight reads wave-broadcast float4.
__device__ __forceinline__ void gemm32x96(
    const float* __restrict__ src, const float* __restrict__ W,
    const float* __restrict__ bias, float* __restrict__ dst)
{
    int tid = threadIdx.x;
    int r = tid & 31;
    float a[96];
    #pragma unroll
    for (int k = 0; k < 96; k += 4) {
        float4 v = *(const float4*)&src[r * 100 + k];
        a[k] = v.x; a[k + 1] = v.y; a[k + 2] = v.z; a[k + 3] = v.w;
    }
    int c0 = tid >> 5;
    for (int j = 0; j < 12; ++j) {
        int c = c0 + 8 * j;
        float acc = bias[c];
        #pragma unroll
        for (int k = 0; k < 96; k += 4) {
            float4 w = *(const float4*)&W[c * 96 + k];
            acc += a[k] * w.x + a[k + 1] * w.y + a[k + 2] * w.z + a[k + 3] * w.w;
        }
        dst[r * 100 + c] = acc;
    }
}

// One direction of cross attention for 4 windows (32 tokens).
__device__ void attn_phase(
    const float* xq, const float* xkv, const float* __restrict__ wp,
    const float* __restrict__ Wo, const float* __restrict__ bo,
    float* __restrict__ Xres, long g0,
    float* P0, float* P1, float* P2, float* Oo)
{
    int tid = threadIdx.x;
    gemm32x96(xq,  wp,         wp + 64512, P0);  // Q (scale+qn folded)
    gemm32x96(xkv, wp + 9216,  wp + 64608, P1);  // K (kvn of other stream folded)
    gemm32x96(xkv, wp + 18432, wp + 64704, P2);  // V
    __syncthreads();
    if (tid < 128) {
        int win = tid >> 5, hd = (tid >> 3) & 3, q = tid & 7;
        int tq = win * 8 + q, ko = hd * 24;
        float sc[8]; float mx = -1e30f;
        for (int j = 0; j < 8; ++j) {
            float s = 0.f;
            int tk = win * 8 + j;
            #pragma unroll
            for (int d = 0; d < 24; ++d) s += P0[tq * 100 + ko + d] * P1[tk * 100 + ko + d];
            sc[j] = s; mx = fmaxf(mx, s);
        }
        float sum = 0.f;
        for (int j = 0; j < 8; ++j) { sc[j] = expf(sc[j] - mx); sum += sc[j]; }
        float inv = 1.f / sum;
        #pragma unroll
        for (int d = 0; d < 24; ++d) {
            float o = 0.f;
            for (int j = 0; j < 8; ++j) o += sc[j] * P2[(win * 8 + j) * 100 + ko + d];
            Oo[tq * 100 + ko + d] = o * inv;
        }
    }
    __syncthreads();
    gemm32x96(Oo, Wo, bo, P0);  // out-proj into dead Q buffer
    __syncthreads();
    for (int i = tid; i < 3072; i += 256) {
        int t = i / 96, c = i % 96;
        Xres[(g0 + t) * 96 + c] += P0[t * 100 + c];
    }
    __syncthreads();
}

// K2: fused cross-MHA, both streams, 4 windows per block. grid 6912.
__global__ __launch_bounds__(256) void k_attn(
    float* __restrict__ Xf, float* __restrict__ Xb,
    const float* __restrict__ Mf, const float* __restrict__ Rf,
    const float* __restrict__ Mb, const float* __restrict__ Rb,
    const float* __restrict__ wpf, const float* __restrict__ wpb,
    const float* __restrict__ Wof, const float* __restrict__ bof,
    const float* __restrict__ Wob, const float* __restrict__ bob)
{
    __shared__ __align__(16) float smem[6 * 3200];
    float* xf = smem;            float* xb = smem + 3200;
    float* P0 = smem + 6400;     float* P1 = smem + 9600;
    float* P2 = smem + 12800;    float* Oo = smem + 16000;
    int tid = threadIdx.x;
    long g0 = (long)blockIdx.x * 32;
    for (int i = tid; i < 3072; i += 256) {
        int t = i / 96, c = i % 96;
        long g = g0 + t;
        xf[t * 100 + c] = (Xf[g * 96 + c] - Mf[g]) * Rf[g];
        xb[t * 100 + c] = (Xb[g * 96 + c] - Mb[g]) * Rb[g];
    }
    __syncthreads();
    attn_phase(xf, xb, wpf, Wof, bof, Xf, g0, P0, P1, P2, Oo);
    attn_phase(xb, xf, wpb, Wob, bob, Xb, g0, P0, P1, P2, Oo);
}

// ---------------------------------------------------------------------------
// K3: fused FFN (LN folded into W1'), 32 rows/block, in-place residual.
// grid 13824 (first 6912 fg, rest bg).
__global__ __launch_bounds__(256) void k_ffn(
    float* __restrict__ Xf, float* __restrict__ Xb,
    const float* __restrict__ wpf, const float* __restrict__ wpb,
    const float* __restrict__ W2f, const float* __restrict__ b2f,
    const float* __restrict__ W2b, const float* __restrict__ b2b)
{
    __shared__ __align__(16) float s1[3200];
    __shared__ __align__(16) float s2[32 * 388];
    __shared__ float smv[64];
    int blk = blockIdx.x, tid = threadIdx.x;
    float* X; const float* wp; const float* W2; const float* b2;
    if (blk < 6912) { X = Xf; wp = wpf; W2 = W2f; b2 = b2f; }
    else            { X = Xb; wp = wpb; W2 = W2b; b2 = b2b; blk -= 6912; }
    long r0 = (long)blk * 32;
    for (int i = tid; i < 3072; i += 256) {
        int t = i / 96, c = i % 96;
        s1[t * 100 + c] = X[(r0 + t) * 96 + c];
    }
    __syncthreads();
    if (tid < 32) {
        float s = 0.f, ss = 0.f;
        for (int c = 0; c < 96; ++c) { float v = s1[tid * 100 + c]; s += v; ss += v * v; }
        float m = s * (1.f / 96.f);
        float var = ss * (1.f / 96.f) - m * m;
        smv[tid] = m; smv[32 + tid] = rsqrtf(var + 1e-5f);
    }
    __syncthreads();
    for (int i = tid; i < 3072; i += 256) {
        int t = i / 96, c = i % 96;
        s1[t * 100 + c] = (s1[t * 100 + c] - smv[t]) * smv[32 + t];
    }
    __syncthreads();
    // GEMM1: [32x96] @ W1'^T -> gelu -> s2[32][388 stride]
    {
        int r = tid & 31, c0 = tid >> 5;
        float a[96];
        #pragma unroll
        for (int k = 0; k < 96; k += 4) {
            float4 v = *(const float4*)&s1[r * 100 + k];
            a[k] = v.x; a[k + 1] = v.y; a[k + 2] = v.z; a[k + 3] = v.w;
        }
        const float* W1 = wp + 27648; const float* b1 = wp + 64800;
        for (int j = 0; j < 48; ++j) {
            int c = c0 + 8 * j;
            float acc = b1[c];
            #pragma unroll
            for (int k = 0; k < 96; k += 4) {
                float4 w = *(const float4*)&W1[c * 96 + k];
                acc += a[k] * w.x + a[k + 1] * w.y + a[k + 2] * w.z + a[k + 3] * w.w;
            }
            s2[r * 388 + c] = gelu_f(acc);
        }
    }
    __syncthreads();
    // GEMM2: [32x384] @ W2^T, K chunked by 96; residual add.
    {
        int r = tid & 31, c0 = tid >> 5;
        float acc[12];
        #pragma unroll
        for (int j = 0; j < 12; ++j) acc[j] = b2[c0 + 8 * j];
        for (int ch = 0; ch < 4; ++ch) {
            float a[96];
            #pragma unroll
            for (int k = 0; k < 96; k += 4) {
                float4 v = *(const float4*)&s2[r * 388 + ch * 96 + k];
                a[k] = v.x; a[k + 1] = v.y; a[k + 2] = v.z; a[k + 3] = v.w;
            }
            for (int j = 0; j < 12; ++j) {
                int c = c0 + 8 * j;
                float s = 0.f;
                #pragma unroll
                for (int k = 0; k < 96; k += 4) {
                    float4 w = *(const float4*)&W2[c * 384 + ch * 96 + k];
                    s += a[k] * w.x + a[k + 1] * w.y + a[k + 2] * w.z + a[k + 3] * w.w;
                }
                acc[j] += s;
            }
        }
        #pragma unroll
        for (int j = 0; j < 12; ++j) s1[r * 100 + c0 + 8 * j] = acc[j];
    }
    __syncthreads();
    for (int i = tid; i < 3072; i += 256) {
        int t = i / 96, c = i % 96;
        X[(r0 + t) * 96 + c] += s1[t * 100 + c];
    }
}

// ---------------------------------------------------------------------------
// K4: 1x1x1 conv in-place (per-row matmul). grid 13824.
__global__ __launch_bounds__(256) void k_conv(
    float* __restrict__ Xf, float* __restrict__ Xb,
    const float* __restrict__ cwf, const float* __restrict__ cbf,
    const float* __restrict__ cwb, const float* __restrict__ cbb)
{
    __shared__ __align__(16) float s1[3200];
    __shared__ __align__(16) float s2[3200];
    int blk = blockIdx.x, tid = threadIdx.x;
    float* X; const float* cw; const float* cb;
    if (blk < 6912) { X = Xf; cw = cwf; cb = cbf; }
    else            { X = Xb; cw = cwb; cb = cbb; blk -= 6912; }
    long r0 = (long)blk * 32;
    for (int i = tid; i < 3072; i += 256) {
        int t = i / 96, c = i % 96;
        s1[t * 100 + c] = X[(r0 + t) * 96 + c];
    }
    __syncthreads();
    gemm32x96(s1, cw, cb, s2);
    __syncthreads();
    for (int i = tid; i < 3072; i += 256) {
        int t = i / 96, c = i % 96;
        X[(r0 + t) * 96 + c] = s2[t * 100 + c];
    }
}

// ---------------------------------------------------------------------------
// K5: InstanceNorm partial sums (deterministic two-level). grid 216, block 384.
__global__ __launch_bounds__(384) void k_instats(
    const float* __restrict__ Xf, const float* __restrict__ Xb,
    float* __restrict__ partial)
{
    __shared__ float red[768];
    int blk = blockIdx.x;
    const float* X = (blk < 108) ? Xf : Xb;
    int rem = blk % 108;
    int b = rem / 54, chunk = rem % 54;
    int tid = threadIdx.x;
    int c = tid % 96, slot = tid / 96;
    long base = (long)b * TOK_PER_B + chunk * 2048;
    float s = 0.f, ss = 0.f;
    for (int i = 0; i < 512; ++i) {
        float v = X[(base + i * 4 + slot) * 96 + c];
        s += v; ss += v * v;
    }
    red[tid] = s; red[384 + tid] = ss;
    __syncthreads();
    if (tid < 96) {
        float S  = red[tid] + red[96 + tid] + red[192 + tid] + red[288 + tid];
        float SS = red[384 + tid] + red[480 + tid] + red[576 + tid] + red[672 + tid];
        partial[((long)blockIdx.x * 96 + tid) * 2]     = S;
        partial[((long)blockIdx.x * 96 + tid) * 2 + 1] = SS;
    }
}

// K6: finalize IN stats: 384 = (stream, b, c) combos.
__global__ __launch_bounds__(384) void k_infin(
    const float* __restrict__ partial, float* __restrict__ inMR)
{
    int tid = threadIdx.x;
    int s = tid / 192, rem = tid % 192, b = rem / 96, c = rem % 96;
    float S = 0.f, SS = 0.f;
    for (int ch = 0; ch < 54; ++ch) {
        int blk = s * 108 + b * 54 + ch;
        S  += partial[(blk * 96 + c) * 2];
        SS += partial[(blk * 96 + c) * 2 + 1];
    }
    float m = S * (1.f / 110592.f);
    float var = SS * (1.f / 110592.f) - m * m;
    inMR[tid * 2] = m;
    inMR[tid * 2 + 1] = rsqrtf(var + 1e-5f);
}

// ---------------------------------------------------------------------------
// K7: IN affine + GELU + window-reverse scatter to output. grid 2304.
__global__ __launch_bounds__(256) void k_scatter(
    const float* __restrict__ Xf, const float* __restrict__ Xb,
    const float* __restrict__ inMR,
    const float* __restrict__ iwf, const float* __restrict__ ibf,
    const float* __restrict__ iwb, const float* __restrict__ ibb,
    float* __restrict__ out)
{
    __shared__ float tile[192 * 97];
    int blk = blockIdx.x, s = 0;
    const float* X = Xf; const float* iw = iwf; const float* ib = ibf;
    if (blk >= 1152) { s = 1; X = Xb; iw = iwb; ib = ibb; blk -= 1152; }
    int b = blk / 576, rem = blk % 576, dw = rem / 24, hw = rem % 24;
    int tid = threadIdx.x;
    long base = ((((long)b * 24 + dw) * 24 + hw) * 24) * 8;
    for (int i = tid; i < 192 * 96; i += 256) {
        int t = i / 96, c = i % 96;
        tile[t * 97 + c] = X[(base + t) * 96 + c];
    }
    __syncthreads();
    float* o = out + (long)s * STREAM_ELEMS;
    for (int i = tid; i < 384 * 48; i += 256) {
        int r = i / 48, w = i % 48;
        int c = r >> 2, d_off = (r >> 1) & 1, h_off = r & 1;
        int t = (w >> 1) * 8 + d_off * 4 + h_off * 2 + (w & 1);
        float v = tile[t * 97 + c];
        float m  = inMR[((s * 2 + b) * 96 + c) * 2];
        float rr = inMR[((s * 2 + b) * 96 + c) * 2 + 1];
        v = (v - m) * rr * iw[c] + ib[c];
        o[((((long)b * 96 + c) * 48 + dw * 2 + d_off) * 48 + hw * 2 + h_off) * 48 + w] = gelu_f(v);
    }
}

// ---------------------------------------------------------------------------
extern "C" void kernel_launch(void* const* d_in, const int* in_sizes, int n_in,
                              void* d_out, int out_size, void* d_ws, size_t ws_size,
                              hipStream_t stream)
{
    #define IN(i) ((const float*)d_in[i])
    const float* fg = IN(0);
    const float* bg = IN(1);

    float* ws = (float*)d_ws;
    float* Xf = ws;
    float* Xb = ws + STREAM_ELEMS;
    float* Mf = ws + 2L * STREAM_ELEMS;
    float* Rf = Mf + G_TOK;
    float* Mb = Rf + G_TOK;
    float* Rb = Mb + G_TOK;
    float* wpf = Rb + G_TOK;
    float* wpb = wpf + 65536;
    float* partial = wpb + 65536;
    float* inMR = partial + 216 * 96 * 2;

    // Fold LN affines into weights.
    // fg: Wi=6 bi=7 W1=12 b1=13 qn=(2,3) kvn_other=bg_kvn=(22,23) ffn=(10,11)
    k_fold<<<1, 256, 0, stream>>>(IN(6), IN(7), IN(12), IN(13),
                                  IN(2), IN(3), IN(22), IN(23), IN(10), IN(11), wpf);
    // bg: Wi=24 bi=25 W1=30 b1=31 qn=(20,21) kvn_other=fg_kvn=(4,5) ffn=(28,29)
    k_fold<<<1, 256, 0, stream>>>(IN(24), IN(25), IN(30), IN(31),
                                  IN(20), IN(21), IN(4), IN(5), IN(28), IN(29), wpb);

    k_gather<<<2304, 256, 0, stream>>>(fg, bg, Xf, Xb, Mf, Rf, Mb, Rb);

    k_attn<<<6912, 256, 0, stream>>>(Xf, Xb, Mf, Rf, Mb, Rb, wpf, wpb,
                                     IN(8), IN(9), IN(26), IN(27));

    k_ffn<<<13824, 256, 0, stream>>>(Xf, Xb, wpf, wpb,
                                     IN(14), IN(15), IN(32), IN(33));

    k_conv<<<13824, 256, 0, stream>>>(Xf, Xb, IN(16), IN(17), IN(34), IN(35));

    k_instats<<<216, 384, 0, stream>>>(Xf, Xb, partial);
    k_infin<<<1, 384, 0, stream>>>(partial, inMR);

    k_scatter<<<2304, 256, 0, stream>>>(Xf, Xb, inMR,
                                        IN(18), IN(19), IN(36), IN(37),
                                        (float*)d_out);
    #undef IN
}

// Round 2
// 1068.484 us; speedup vs baseline: 7.7792x; 7.7792x over previous
//
#include <hip/hip_runtime.h>
#include <hip/hip_bf16.h>

// LocalCrossAttentionBlock3D — R1: bf16 MFMA everywhere.
// B=2, C=96, D=H=W=48, NH=4, dh=24, WIN=2^3, HID=384.
// Token-major X[g][96], g = n*8 + l, n=((b*24+dw)*24+hw)*24+ww, l=ld*4+lh*2+lw.

#define G_TOK 221184
#define TOK_PER_B 110592
#define STREAM_ELEMS 21233664  // G_TOK*96

typedef __attribute__((ext_vector_type(8))) short short8;
typedef __attribute__((ext_vector_type(4))) float f32x4;
typedef unsigned short ushort_t;
typedef unsigned int uint_t;

#define MFMA16 __builtin_amdgcn_mfma_f32_16x16x32_bf16

__device__ __forceinline__ float gelu_f(float x) {
    return 0.5f * x * (1.0f + erff(x * 0.70710678118654752f));
}
__device__ __forceinline__ uint_t f2bfbits(float f) {   // RNE, bf16 in low 16
    uint_t u = __float_as_uint(f);
    return (u + 0x7fffu + ((u >> 16) & 1u)) >> 16;
}
__device__ __forceinline__ uint_t pack2(float a, float b) {
    return f2bfbits(a) | (f2bfbits(b) << 16);
}
__device__ __forceinline__ void bf24_load(const ushort_t* p, float* o) {
    const uint4* q = (const uint4*)p;
    #pragma unroll
    for (int u = 0; u < 3; ++u) {
        uint4 v = q[u];
        o[u*8+0] = __uint_as_float(v.x << 16); o[u*8+1] = __uint_as_float(v.x & 0xffff0000u);
        o[u*8+2] = __uint_as_float(v.y << 16); o[u*8+3] = __uint_as_float(v.y & 0xffff0000u);
        o[u*8+4] = __uint_as_float(v.z << 16); o[u*8+5] = __uint_as_float(v.z & 0xffff0000u);
        o[u*8+6] = __uint_as_float(v.w << 16); o[u*8+7] = __uint_as_float(v.w & 0xffff0000u);
    }
}

// ---------------------------------------------------------------------------
// K0: fold LN affines (and 1/sqrt(dh)) into bf16 weights; f32 biases.
// Weight block (ushorts): Wq'@0  Wk'@9216  Wv'@18432  Wo@27648  W1'@36864
//                         W2@73728  Wc@110592   (total 119808)
// Bias block (floats):    bq'@0 bk'@96 bv'@192 bo@288 b1'@384 b2@768 (864)
__global__ __launch_bounds__(256) void k_fold(
    const float* __restrict__ Wi, const float* __restrict__ bi,
    const float* __restrict__ Wo, const float* __restrict__ bo,
    const float* __restrict__ W1, const float* __restrict__ b1,
    const float* __restrict__ W2, const float* __restrict__ b2,
    const float* __restrict__ Wc,
    const float* __restrict__ qnw, const float* __restrict__ qnb,
    const float* __restrict__ kvw, const float* __restrict__ kvb,
    const float* __restrict__ fnw, const float* __restrict__ fnb,
    ushort_t* __restrict__ w, float* __restrict__ bs)
{
    const float scale = 0.20412414523193150f;  // 1/sqrt(24)
    int tid = threadIdx.x;
    for (int i = tid; i < 9216; i += 256) {
        int k = i % 96;
        w[i]          = (ushort_t)f2bfbits(Wi[i] * qnw[k] * scale);
        w[9216 + i]   = (ushort_t)f2bfbits(Wi[9216 + i] * kvw[k]);
        w[18432 + i]  = (ushort_t)f2bfbits(Wi[18432 + i] * kvw[k]);
        w[27648 + i]  = (ushort_t)f2bfbits(Wo[i]);
        w[110592 + i] = (ushort_t)f2bfbits(Wc[i]);
    }
    for (int i = tid; i < 36864; i += 256) {
        int k = i % 96;
        w[36864 + i] = (ushort_t)f2bfbits(W1[i] * fnw[k]);
        w[73728 + i] = (ushort_t)f2bfbits(W2[i]);
    }
    for (int c = tid; c < 96; c += 256) {
        float s0 = bi[c], s1 = bi[96 + c], s2 = bi[192 + c];
        for (int k = 0; k < 96; ++k) {
            s0 += qnb[k] * Wi[c * 96 + k];
            s1 += kvb[k] * Wi[(96 + c) * 96 + k];
            s2 += kvb[k] * Wi[(192 + c) * 96 + k];
        }
        bs[c] = s0 * scale; bs[96 + c] = s1; bs[192 + c] = s2; bs[288 + c] = bo[c];
        bs[768 + c] = b2[c];
    }
    for (int c = tid; c < 384; c += 256) {
        float s = b1[c];
        for (int k = 0; k < 96; ++k) s += fnb[k] * W1[c * 96 + k];
        bs[384 + c] = s;
    }
}

// ---------------------------------------------------------------------------
// K1: gather [B,C,D,H,W] -> token-major X[G,96].
__global__ __launch_bounds__(256) void k_gather(
    const float* __restrict__ srcf, const float* __restrict__ srcb,
    float* __restrict__ Xf, float* __restrict__ Xb)
{
    __shared__ float tile[192 * 97];
    int blk = blockIdx.x;
    const float* src; float* X;
    if (blk < 1152) { src = srcf; X = Xf; }
    else            { src = srcb; X = Xb; blk -= 1152; }
    int b = blk / 576, rem = blk % 576, dw = rem / 24, hw = rem % 24;
    int tid = threadIdx.x;
    for (int i = tid; i < 384 * 48; i += 256) {
        int r = i / 48, w = i % 48;
        int c = r >> 2, d_off = (r >> 1) & 1, h_off = r & 1;
        float v = src[((((long)b * 96 + c) * 48 + dw * 2 + d_off) * 48 + hw * 2 + h_off) * 48 + w];
        int t = (w >> 1) * 8 + d_off * 4 + h_off * 2 + (w & 1);
        tile[t * 97 + c] = v;
    }
    __syncthreads();
    long base = ((((long)b * 24 + dw) * 24 + hw) * 24) * 8;
    for (int i = tid; i < 192 * 96; i += 256) {
        int t = i / 96, c = i % 96;
        X[(base + t) * 96 + c] = tile[t * 97 + c];
    }
}

// ---------------------------------------------------------------------------
// MFMA GEMM: 16 rows (wave-local) x 96 cols, K=96; A from LDS (stride 104 bf16),
// B = W[96][96] bf16 row-major (k-contiguous); D -> bf16 LDS (stride 104).
__device__ __forceinline__ void gemm_qkv(
    const ushort_t* __restrict__ xs, const ushort_t* __restrict__ W,
    const float* __restrict__ bias, ushort_t* __restrict__ outs,
    int mbase, int l15, int kb)
{
    const int abase = (mbase + l15) * 104 + kb * 8;
    short8 a0 = *(const short8*)&xs[abase];
    short8 a1 = *(const short8*)&xs[abase + 32];
    short8 a2 = *(const short8*)&xs[abase + 64];
    #pragma unroll
    for (int t = 0; t < 6; ++t) {
        int c = t * 16 + l15;
        float bv = bias[c];
        f32x4 acc = {bv, bv, bv, bv};
        acc = MFMA16(a0, *(const short8*)&W[c * 96 + kb * 8], acc, 0, 0, 0);
        acc = MFMA16(a1, *(const short8*)&W[c * 96 + 32 + kb * 8], acc, 0, 0, 0);
        acc = MFMA16(a2, *(const short8*)&W[c * 96 + 64 + kb * 8], acc, 0, 0, 0);
        #pragma unroll
        for (int i = 0; i < 4; ++i)
            outs[(mbase + kb * 4 + i) * 104 + c] = (ushort_t)f2bfbits(acc[i]);
    }
}

// K2: fused cross-MHA, both streams, 64 tokens (8 windows) per block. grid 3456.
__global__ __launch_bounds__(256) void k_attn(
    float* __restrict__ Xf, float* __restrict__ Xb,
    const ushort_t* __restrict__ wf, const ushort_t* __restrict__ wb,
    const float* __restrict__ bsf, const float* __restrict__ bsb)
{
    __shared__ ushort_t xbf[2][64 * 104];
    __shared__ ushort_t qs[64 * 104], ks_[64 * 104], vs[64 * 104];
    __shared__ float mr[2][64][2];
    int tid = threadIdx.x;
    long g0 = (long)blockIdx.x * 64;

    {   // per-token LN stats, 4 threads per token (same wave -> shfl ok)
        int t = tid >> 2, p = tid & 3;
        const float* Xs0 = Xf; const float* Xs1 = Xb;
        #pragma unroll
        for (int s = 0; s < 2; ++s) {
            const float* px = (s ? Xs1 : Xs0) + (g0 + t) * 96 + p * 24;
            float s1 = 0.f, s2 = 0.f;
            #pragma unroll
            for (int j = 0; j < 6; ++j) {
                float4 v = *(const float4*)(px + j * 4);
                s1 += v.x + v.y + v.z + v.w;
                s2 += v.x * v.x + v.y * v.y + v.z * v.z + v.w * v.w;
            }
            s1 += __shfl_xor(s1, 1); s1 += __shfl_xor(s1, 2);
            s2 += __shfl_xor(s2, 1); s2 += __shfl_xor(s2, 2);
            if (p == 0) {
                float m = s1 * (1.f / 96.f);
                float var = s2 * (1.f / 96.f) - m * m;
                mr[s][t][0] = m; mr[s][t][1] = rsqrtf(var + 1e-5f);
            }
        }
    }
    __syncthreads();
    for (int i = tid; i < 64 * 24; i += 256) {
        int t = i / 24, c4 = (i % 24) * 4;
        float m0 = mr[0][t][0], r0 = mr[0][t][1];
        float m1 = mr[1][t][0], r1 = mr[1][t][1];
        float4 v = *(const float4*)&Xf[(g0 + t) * 96 + c4];
        uint2 pz;
        pz.x = pack2((v.x - m0) * r0, (v.y - m0) * r0);
        pz.y = pack2((v.z - m0) * r0, (v.w - m0) * r0);
        *(uint2*)&xbf[0][t * 104 + c4] = pz;
        v = *(const float4*)&Xb[(g0 + t) * 96 + c4];
        pz.x = pack2((v.x - m1) * r1, (v.y - m1) * r1);
        pz.y = pack2((v.z - m1) * r1, (v.w - m1) * r1);
        *(uint2*)&xbf[1][t * 104 + c4] = pz;
    }
    __syncthreads();
    // everything below is wave-local (wave w owns rows 16w..16w+15 = windows 2w,2w+1)

    int lane = tid & 63, wv = tid >> 6, l15 = lane & 15, kb = lane >> 4;
    int mbase = wv * 16;
    int win = tid >> 5, hd = (tid >> 3) & 3, q8 = tid & 7;
    int tq = win * 8 + q8, ko = hd * 24;

    #pragma unroll
    for (int dir = 0; dir < 2; ++dir) {
        const ushort_t* W = dir ? wb : wf;
        const float* bs = dir ? bsb : bsf;
        const ushort_t* xq = xbf[dir];
        const ushort_t* xkv = xbf[dir ^ 1];
        float* X = dir ? Xb : Xf;

        gemm_qkv(xq,  W,         bs,       qs,  mbase, l15, kb);
        gemm_qkv(xkv, W + 9216,  bs + 96,  ks_, mbase, l15, kb);
        gemm_qkv(xkv, W + 18432, bs + 192, vs,  mbase, l15, kb);

        // attention: one thread per (window, head, q) — all wave-local rows
        {
            float qf[24];
            bf24_load(&qs[tq * 104 + ko], qf);
            float sc[8], mx = -1e30f;
            #pragma unroll
            for (int j = 0; j < 8; ++j) {
                float kf[24];
                bf24_load(&ks_[(win * 8 + j) * 104 + ko], kf);
                float s = 0.f;
                #pragma unroll
                for (int d = 0; d < 24; ++d) s += qf[d] * kf[d];
                sc[j] = s; mx = fmaxf(mx, s);
            }
            float sum = 0.f;
            #pragma unroll
            for (int j = 0; j < 8; ++j) { sc[j] = __expf(sc[j] - mx); sum += sc[j]; }
            float inv = 1.f / sum;
            float of[24];
            #pragma unroll
            for (int d = 0; d < 24; ++d) of[d] = 0.f;
            #pragma unroll
            for (int j = 0; j < 8; ++j) {
                float vf[24];
                bf24_load(&vs[(win * 8 + j) * 104 + ko], vf);
                #pragma unroll
                for (int d = 0; d < 24; ++d) of[d] += sc[j] * vf[d];
            }
            uint4* od = (uint4*)&qs[tq * 104 + ko];   // reuse Q buffer for O
            #pragma unroll
            for (int u = 0; u < 3; ++u) {
                uint4 pw;
                pw.x = pack2(of[u*8+0] * inv, of[u*8+1] * inv);
                pw.y = pack2(of[u*8+2] * inv, of[u*8+3] * inv);
                pw.z = pack2(of[u*8+4] * inv, of[u*8+5] * inv);
                pw.w = pack2(of[u*8+6] * inv, of[u*8+7] * inv);
                od[u] = pw;
            }
        }

        // out-proj + residual into X (f32 global)
        {
            const int abase = (mbase + l15) * 104 + kb * 8;
            short8 a0 = *(const short8*)&qs[abase];
            short8 a1 = *(const short8*)&qs[abase + 32];
            short8 a2 = *(const short8*)&qs[abase + 64];
            const ushort_t* Wo = W + 27648;
            const float* bo = bs + 288;
            #pragma unroll
            for (int t = 0; t < 6; ++t) {
                int c = t * 16 + l15;
                float bv = bo[c];
                f32x4 acc = {bv, bv, bv, bv};
                acc = MFMA16(a0, *(const short8*)&Wo[c * 96 + kb * 8], acc, 0, 0, 0);
                acc = MFMA16(a1, *(const short8*)&Wo[c * 96 + 32 + kb * 8], acc, 0, 0, 0);
                acc = MFMA16(a2, *(const short8*)&Wo[c * 96 + 64 + kb * 8], acc, 0, 0, 0);
                #pragma unroll
                for (int i = 0; i < 4; ++i)
                    X[(g0 + mbase + kb * 4 + i) * 96 + c] += acc[i];
            }
        }
    }
}

// ---------------------------------------------------------------------------
// K3: fused LN->FFN->residual->conv.  64 tokens/block, one stream. grid 6912.
__global__ __launch_bounds__(256) void k_ffn(
    float* __restrict__ Xf, float* __restrict__ Xb,
    const ushort_t* __restrict__ wf, const ushort_t* __restrict__ wb,
    const float* __restrict__ bsf, const float* __restrict__ bsb)
{
    __shared__ float xf32[64 * 100];
    __shared__ ushort_t xb_[64 * 104];
    __shared__ ushort_t H[64 * 104];
    __shared__ float mr[64][2];
    int blk = blockIdx.x, tid = threadIdx.x;
    float* X; const ushort_t* W; const float* bs;
    if (blk < 3456) { X = Xf; W = wf; bs = bsf; }
    else            { X = Xb; W = wb; bs = bsb; blk -= 3456; }
    long g0 = (long)blk * 64;

    for (int i = tid; i < 64 * 24; i += 256) {
        int t = i / 24, c4 = (i % 24) * 4;
        *(float4*)&xf32[t * 100 + c4] = *(const float4*)&X[(g0 + t) * 96 + c4];
    }
    __syncthreads();
    {
        int t = tid >> 2, p = tid & 3;
        float s1 = 0.f, s2 = 0.f;
        #pragma unroll
        for (int j = 0; j < 6; ++j) {
            float4 v = *(const float4*)&xf32[t * 100 + p * 24 + j * 4];
            s1 += v.x + v.y + v.z + v.w;
            s2 += v.x * v.x + v.y * v.y + v.z * v.z + v.w * v.w;
        }
        s1 += __shfl_xor(s1, 1); s1 += __shfl_xor(s1, 2);
        s2 += __shfl_xor(s2, 1); s2 += __shfl_xor(s2, 2);
        if (p == 0) {
            float m = s1 * (1.f / 96.f);
            float var = s2 * (1.f / 96.f) - m * m;
            mr[t][0] = m; mr[t][1] = rsqrtf(var + 1e-5f);
        }
    }
    __syncthreads();
    for (int i = tid; i < 64 * 24; i += 256) {
        int t = i / 24, c4 = (i % 24) * 4;
        float m = mr[t][0], r = mr[t][1];
        float4 v = *(const float4*)&xf32[t * 100 + c4];
        uint2 pz;
        pz.x = pack2((v.x - m) * r, (v.y - m) * r);
        pz.y = pack2((v.z - m) * r, (v.w - m) * r);
        *(uint2*)&xb_[t * 104 + c4] = pz;
    }
    __syncthreads();
    // ---- wave-local from here ----
    int lane = tid & 63, wv = tid >> 6, l15 = lane & 15, kb = lane >> 4;
    int mbase = wv * 16;
    const int abase = (mbase + l15) * 104 + kb * 8;
    short8 a0 = *(const short8*)&xb_[abase];
    short8 a1 = *(const short8*)&xb_[abase + 32];
    short8 a2 = *(const short8*)&xb_[abase + 64];
    const ushort_t* W1 = W + 36864;
    const ushort_t* W2 = W + 73728;
    const ushort_t* Wc = W + 110592;
    const float* b1 = bs + 384;
    const float* b2 = bs + 768;

    f32x4 acc2[6];
    #pragma unroll
    for (int t = 0; t < 6; ++t) {
        float bb = b2[t * 16 + l15];
        acc2[t] = {bb, bb, bb, bb};
    }
    for (int ch = 0; ch < 4; ++ch) {
        #pragma unroll
        for (int t = 0; t < 6; ++t) {      // GEMM1 chunk -> gelu -> H
            int c = ch * 96 + t * 16 + l15;
            float bb = b1[c];
            f32x4 acc = {bb, bb, bb, bb};
            acc = MFMA16(a0, *(const short8*)&W1[c * 96 + kb * 8], acc, 0, 0, 0);
            acc = MFMA16(a1, *(const short8*)&W1[c * 96 + 32 + kb * 8], acc, 0, 0, 0);
            acc = MFMA16(a2, *(const short8*)&W1[c * 96 + 64 + kb * 8], acc, 0, 0, 0);
            #pragma unroll
            for (int i = 0; i < 4; ++i)
                H[(mbase + kb * 4 + i) * 104 + t * 16 + l15] =
                    (ushort_t)f2bfbits(gelu_f(acc[i]));
        }
        short8 h0 = *(const short8*)&H[abase];
        short8 h1 = *(const short8*)&H[abase + 32];
        short8 h2 = *(const short8*)&H[abase + 64];
        #pragma unroll
        for (int t = 0; t < 6; ++t) {      // GEMM2 partial
            int c = t * 16 + l15;
            const ushort_t* w2r = &W2[c * 384 + ch * 96];
            acc2[t] = MFMA16(h0, *(const short8*)&w2r[kb * 8], acc2[t], 0, 0, 0);
            acc2[t] = MFMA16(h1, *(const short8*)&w2r[32 + kb * 8], acc2[t], 0, 0, 0);
            acc2[t] = MFMA16(h2, *(const short8*)&w2r[64 + kb * 8], acc2[t], 0, 0, 0);
        }
    }
    // residual in f32, store y as bf16 A-operand for conv (reuse xb_)
    #pragma unroll
    for (int t = 0; t < 6; ++t) {
        #pragma unroll
        for (int i = 0; i < 4; ++i) {
            int row = mbase + kb * 4 + i, col = t * 16 + l15;
            float y = acc2[t][i] + xf32[row * 100 + col];
            xb_[row * 104 + col] = (ushort_t)f2bfbits(y);
        }
    }
    // conv (1x1x1): X = y @ Wc^T   (bias dropped — cancels in InstanceNorm)
    short8 c0 = *(const short8*)&xb_[abase];
    short8 c1 = *(const short8*)&xb_[abase + 32];
    short8 c2 = *(const short8*)&xb_[abase + 64];
    #pragma unroll
    for (int t = 0; t < 6; ++t) {
        int c = t * 16 + l15;
        f32x4 acc = {0.f, 0.f, 0.f, 0.f};
        acc = MFMA16(c0, *(const short8*)&Wc[c * 96 + kb * 8], acc, 0, 0, 0);
        acc = MFMA16(c1, *(const short8*)&Wc[c * 96 + 32 + kb * 8], acc, 0, 0, 0);
        acc = MFMA16(c2, *(const short8*)&Wc[c * 96 + 64 + kb * 8], acc, 0, 0, 0);
        #pragma unroll
        for (int i = 0; i < 4; ++i)
            X[(g0 + mbase + kb * 4 + i) * 96 + c] = acc[i];
    }
}

// ---------------------------------------------------------------------------
// K5: InstanceNorm partial sums. grid 216, block 384.
__global__ __launch_bounds__(384) void k_instats(
    const float* __restrict__ Xf, const float* __restrict__ Xb,
    float* __restrict__ partial)
{
    __shared__ float red[768];
    int blk = blockIdx.x;
    const float* X = (blk < 108) ? Xf : Xb;
    int rem = blk % 108;
    int b = rem / 54, chunk = rem % 54;
    int tid = threadIdx.x;
    int c = tid % 96, slot = tid / 96;
    long base = (long)b * TOK_PER_B + chunk * 2048;
    float s = 0.f, ss = 0.f;
    for (int i = 0; i < 512; ++i) {
        float v = X[(base + i * 4 + slot) * 96 + c];
        s += v; ss += v * v;
    }
    red[tid] = s; red[384 + tid] = ss;
    __syncthreads();
    if (tid < 96) {
        float S  = red[tid] + red[96 + tid] + red[192 + tid] + red[288 + tid];
        float SS = red[384 + tid] + red[480 + tid] + red[576 + tid] + red[672 + tid];
        partial[((long)blockIdx.x * 96 + tid) * 2]     = S;
        partial[((long)blockIdx.x * 96 + tid) * 2 + 1] = SS;
    }
}

__global__ __launch_bounds__(384) void k_infin(
    const float* __restrict__ partial, float* __restrict__ inMR)
{
    int tid = threadIdx.x;
    int s = tid / 192, rem = tid % 192, b = rem / 96, c = rem % 96;
    float S = 0.f, SS = 0.f;
    for (int ch = 0; ch < 54; ++ch) {
        int blk = s * 108 + b * 54 + ch;
        S  += partial[(blk * 96 + c) * 2];
        SS += partial[(blk * 96 + c) * 2 + 1];
    }
    float m = S * (1.f / 110592.f);
    float var = SS * (1.f / 110592.f) - m * m;
    inMR[tid * 2] = m;
    inMR[tid * 2 + 1] = rsqrtf(var + 1e-5f);
}

// ---------------------------------------------------------------------------
// K7: IN affine + GELU + window-reverse scatter. grid 2304.
__global__ __launch_bounds__(256) void k_scatter(
    const float* __restrict__ Xf, const float* __restrict__ Xb,
    const float* __restrict__ inMR,
    const float* __restrict__ iwf, const float* __restrict__ ibf,
    const float* __restrict__ iwb, const float* __restrict__ ibb,
    float* __restrict__ out)
{
    __shared__ float tile[192 * 97];
    int blk = blockIdx.x, s = 0;
    const float* X = Xf; const float* iw = iwf; const float* ib = ibf;
    if (blk >= 1152) { s = 1; X = Xb; iw = iwb; ib = ibb; blk -= 1152; }
    int b = blk / 576, rem = blk % 576, dw = rem / 24, hw = rem % 24;
    int tid = threadIdx.x;
    long base = ((((long)b * 24 + dw) * 24 + hw) * 24) * 8;
    for (int i = tid; i < 192 * 96; i += 256) {
        int t = i / 96, c = i % 96;
        tile[t * 97 + c] = X[(base + t) * 96 + c];
    }
    __syncthreads();
    float* o = out + (long)s * STREAM_ELEMS;
    for (int i = tid; i < 384 * 48; i += 256) {
        int r = i / 48, w = i % 48;
        int c = r >> 2, d_off = (r >> 1) & 1, h_off = r & 1;
        int t = (w >> 1) * 8 + d_off * 4 + h_off * 2 + (w & 1);
        float v = tile[t * 97 + c];
        float m  = inMR[((s * 2 + b) * 96 + c) * 2];
        float rr = inMR[((s * 2 + b) * 96 + c) * 2 + 1];
        v = (v - m) * rr * iw[c] + ib[c];
        o[((((long)b * 96 + c) * 48 + dw * 2 + d_off) * 48 + hw * 2 + h_off) * 48 + w] = gelu_f(v);
    }
}

// ---------------------------------------------------------------------------
extern "C" void kernel_launch(void* const* d_in, const int* in_sizes, int n_in,
                              void* d_out, int out_size, void* d_ws, size_t ws_size,
                              hipStream_t stream)
{
    #define IN(i) ((const float*)d_in[i])
    float* ws = (float*)d_ws;
    float* Xf = ws;
    float* Xb = ws + (long)STREAM_ELEMS;
    ushort_t* wW  = (ushort_t*)(ws + 2L * STREAM_ELEMS);   // fg weights (119808 ush)
    ushort_t* wWb = wW + 119808;                           // bg weights
    float* bsf = ws + 2L * STREAM_ELEMS + 119808;          // (239616 ush == 119808 fl)
    float* bsb = bsf + 864;
    float* partial = bsb + 864;                            // 216*96*2
    float* inMR = partial + 41472;

    // fg: Wi=6 bi=7 Wo=8 bo=9 W1=12 b1=13 W2=14 b2=15 Wc=16 qn=(2,3) kvn_other=(22,23) ffn=(10,11)
    k_fold<<<1, 256, 0, stream>>>(IN(6), IN(7), IN(8), IN(9), IN(12), IN(13), IN(14), IN(15), IN(16),
                                  IN(2), IN(3), IN(22), IN(23), IN(10), IN(11), wW, bsf);
    // bg: Wi=24 bi=25 Wo=26 bo=27 W1=30 b1=31 W2=32 b2=33 Wc=34 qn=(20,21) kvn_other=(4,5) ffn=(28,29)
    k_fold<<<1, 256, 0, stream>>>(IN(24), IN(25), IN(26), IN(27), IN(30), IN(31), IN(32), IN(33), IN(34),
                                  IN(20), IN(21), IN(4), IN(5), IN(28), IN(29), wWb, bsb);

    k_gather<<<2304, 256, 0, stream>>>(IN(0), IN(1), Xf, Xb);

    k_attn<<<3456, 256, 0, stream>>>(Xf, Xb, wW, wWb, bsf, bsb);

    k_ffn<<<6912, 256, 0, stream>>>(Xf, Xb, wW, wWb, bsf, bsb);

    k_instats<<<216, 384, 0, stream>>>(Xf, Xb, partial);
    k_infin<<<1, 384, 0, stream>>>(partial, inMR);

    k_scatter<<<2304, 256, 0, stream>>>(Xf, Xb, inMR,
                                        IN(18), IN(19), IN(36), IN(37),
                                        (float*)d_out);
    #undef IN
}

// Round 3
// 967.942 us; speedup vs baseline: 8.5872x; 1.1039x over previous
//
#include <hip/hip_runtime.h>
#include <hip/hip_bf16.h>

// LocalCrossAttentionBlock3D — R2: bf16 X-state, wave-local fused kernels.
// B=2, C=96, D=H=W=48, NH=4, dh=24, WIN=2^3, HID=384.
// Token-major X[g][96] bf16, g = n*8 + l, n=((b*24+dw)*24+hw)*24+ww.

#define G_TOK 221184
#define TOK_PER_B 110592
#define STREAM_ELEMS 21233664  // G_TOK*96

typedef __attribute__((ext_vector_type(8))) short short8;
typedef __attribute__((ext_vector_type(4))) float f32x4;
typedef unsigned short ushort_t;
typedef unsigned int uint_t;

#define MFMA16 __builtin_amdgcn_mfma_f32_16x16x32_bf16

__device__ __forceinline__ float gelu_erf(float x) {
    return 0.5f * x * (1.0f + erff(x * 0.70710678118654752f));
}
__device__ __forceinline__ float gelu_tanh(float x) {
    // x * sigmoid(2*0.79788456*(x + 0.044715 x^3)); |err| < 1e-3
    float u = x * (1.5957691216f + 0.0713548163f * x * x);
    return x / (1.0f + __expf(-u));
}
__device__ __forceinline__ uint_t f2bfbits(float f) {   // RNE
    uint_t u = __float_as_uint(f);
    return (u + 0x7fffu + ((u >> 16) & 1u)) >> 16;
}
__device__ __forceinline__ uint_t pack2(float a, float b) {
    return f2bfbits(a) | (f2bfbits(b) << 16);
}
__device__ __forceinline__ float bf2f(ushort_t v) {
    return __uint_as_float((uint_t)v << 16);
}
__device__ __forceinline__ void unpack8(uint4 v, float* o) {
    o[0] = __uint_as_float(v.x << 16); o[1] = __uint_as_float(v.x & 0xffff0000u);
    o[2] = __uint_as_float(v.y << 16); o[3] = __uint_as_float(v.y & 0xffff0000u);
    o[4] = __uint_as_float(v.z << 16); o[5] = __uint_as_float(v.z & 0xffff0000u);
    o[6] = __uint_as_float(v.w << 16); o[7] = __uint_as_float(v.w & 0xffff0000u);
}
__device__ __forceinline__ uint4 pack8(const float* f) {
    uint4 v;
    v.x = pack2(f[0], f[1]); v.y = pack2(f[2], f[3]);
    v.z = pack2(f[4], f[5]); v.w = pack2(f[6], f[7]);
    return v;
}
__device__ __forceinline__ void bf24_load(const ushort_t* p, float* o) {
    const uint4* q = (const uint4*)p;
    #pragma unroll
    for (int u = 0; u < 3; ++u) unpack8(q[u], o + u * 8);
}

// ---------------------------------------------------------------------------
// K0: fold LN affines (and 1/sqrt(dh)) into bf16 weights; f32 biases.
// Weights (ushorts): Wq'@0 Wk'@9216 Wv'@18432 Wo@27648 W1'@36864 W2@73728 Wc@110592
// Biases (floats):   bq'@0 bk'@96 bv'@192 bo@288 b1'@384 b2@768
__global__ __launch_bounds__(256) void k_fold(
    const float* __restrict__ Wi, const float* __restrict__ bi,
    const float* __restrict__ Wo, const float* __restrict__ bo,
    const float* __restrict__ W1, const float* __restrict__ b1,
    const float* __restrict__ W2, const float* __restrict__ b2,
    const float* __restrict__ Wc,
    const float* __restrict__ qnw, const float* __restrict__ qnb,
    const float* __restrict__ kvw, const float* __restrict__ kvb,
    const float* __restrict__ fnw, const float* __restrict__ fnb,
    ushort_t* __restrict__ w, float* __restrict__ bs)
{
    const float scale = 0.20412414523193150f;
    int tid = threadIdx.x;
    for (int i = tid; i < 9216; i += 256) {
        int k = i % 96;
        w[i]          = (ushort_t)f2bfbits(Wi[i] * qnw[k] * scale);
        w[9216 + i]   = (ushort_t)f2bfbits(Wi[9216 + i] * kvw[k]);
        w[18432 + i]  = (ushort_t)f2bfbits(Wi[18432 + i] * kvw[k]);
        w[27648 + i]  = (ushort_t)f2bfbits(Wo[i]);
        w[110592 + i] = (ushort_t)f2bfbits(Wc[i]);
    }
    for (int i = tid; i < 36864; i += 256) {
        int k = i % 96;
        w[36864 + i] = (ushort_t)f2bfbits(W1[i] * fnw[k]);
        w[73728 + i] = (ushort_t)f2bfbits(W2[i]);
    }
    for (int c = tid; c < 96; c += 256) {
        float s0 = bi[c], s1 = bi[96 + c], s2 = bi[192 + c];
        for (int k = 0; k < 96; ++k) {
            s0 += qnb[k] * Wi[c * 96 + k];
            s1 += kvb[k] * Wi[(96 + c) * 96 + k];
            s2 += kvb[k] * Wi[(192 + c) * 96 + k];
        }
        bs[c] = s0 * scale; bs[96 + c] = s1; bs[192 + c] = s2; bs[288 + c] = bo[c];
        bs[768 + c] = b2[c];
    }
    for (int c = tid; c < 384; c += 256) {
        float s = b1[c];
        for (int k = 0; k < 96; ++k) s += fnb[k] * W1[c * 96 + k];
        bs[384 + c] = s;
    }
}

// ---------------------------------------------------------------------------
// K1: gather [B,C,D,H,W] f32 -> token-major bf16 X[G,96].
__global__ __launch_bounds__(256) void k_gather(
    const float* __restrict__ srcf, const float* __restrict__ srcb,
    ushort_t* __restrict__ Xf, ushort_t* __restrict__ Xb)
{
    __shared__ float tile[192 * 97];
    int blk = blockIdx.x;
    const float* src; ushort_t* X;
    if (blk < 1152) { src = srcf; X = Xf; }
    else            { src = srcb; X = Xb; blk -= 1152; }
    int b = blk / 576, rem = blk % 576, dw = rem / 24, hw = rem % 24;
    int tid = threadIdx.x;
    for (int i = tid; i < 384 * 48; i += 256) {
        int r = i / 48, w = i % 48;
        int c = r >> 2, d_off = (r >> 1) & 1, h_off = r & 1;
        float v = src[((((long)b * 96 + c) * 48 + dw * 2 + d_off) * 48 + hw * 2 + h_off) * 48 + w];
        int t = (w >> 1) * 8 + d_off * 4 + h_off * 2 + (w & 1);
        tile[t * 97 + c] = v;
    }
    __syncthreads();
    long base = ((((long)b * 24 + dw) * 24 + hw) * 24) * 8;
    for (int i = tid; i < 192 * 12; i += 256) {
        int t = i / 12, c8 = i % 12;
        *(uint4*)&X[(base + t) * 96 + c8 * 8] = pack8(&tile[t * 97 + c8 * 8]);
    }
}

// ---------------------------------------------------------------------------
// MFMA GEMM: wave-local 16 rows x 96 cols, K=96; A from LDS (stride 104 bf16).
__device__ __forceinline__ void gemm_qkv(
    const ushort_t* __restrict__ xs, const ushort_t* __restrict__ W,
    const float* __restrict__ bias, ushort_t* __restrict__ outs,
    int mbase, int l15, int kb)
{
    const int abase = (mbase + l15) * 104 + kb * 8;
    short8 a0 = *(const short8*)&xs[abase];
    short8 a1 = *(const short8*)&xs[abase + 32];
    short8 a2 = *(const short8*)&xs[abase + 64];
    #pragma unroll
    for (int t = 0; t < 6; ++t) {
        int c = t * 16 + l15;
        float bv = bias[c];
        f32x4 acc = {bv, bv, bv, bv};
        acc = MFMA16(a0, *(const short8*)&W[c * 96 + kb * 8], acc, 0, 0, 0);
        acc = MFMA16(a1, *(const short8*)&W[c * 96 + 32 + kb * 8], acc, 0, 0, 0);
        acc = MFMA16(a2, *(const short8*)&W[c * 96 + 64 + kb * 8], acc, 0, 0, 0);
        #pragma unroll
        for (int i = 0; i < 4; ++i)
            outs[(mbase + kb * 4 + i) * 104 + c] = (ushort_t)f2bfbits(acc[i]);
    }
}

// K2: fused cross-MHA, both streams, 64 tokens/block. grid 3456.
// Wave-local throughout (wave owns 16 tokens = 2 windows); 2 safety barriers.
__global__ __launch_bounds__(256) void k_attn(
    ushort_t* __restrict__ Xf, ushort_t* __restrict__ Xb,
    const ushort_t* __restrict__ wf, const ushort_t* __restrict__ wb,
    const float* __restrict__ bsf, const float* __restrict__ bsb)
{
    __shared__ ushort_t xbf[2][64 * 104];
    __shared__ ushort_t qs[64 * 104];
    __shared__ ushort_t kv[64 * 104];
    int tid = threadIdx.x;
    int lane = tid & 63, wv = tid >> 6, mbase = wv * 16;
    long g0 = (long)blockIdx.x * 64;
    float* mrf = (float*)&kv[mbase * 104];   // [2][16][2] floats, wave-local

    // P0: per-token LN stats from bf16 X
    {
        int tl = lane >> 2, p = lane & 3;
        #pragma unroll
        for (int s = 0; s < 2; ++s) {
            const ushort_t* px = (s ? Xb : Xf) + (g0 + mbase + tl) * 96 + p * 24;
            float s1 = 0.f, s2 = 0.f;
            #pragma unroll
            for (int u = 0; u < 3; ++u) {
                float f[8]; unpack8(((const uint4*)px)[u], f);
                #pragma unroll
                for (int j = 0; j < 8; ++j) { s1 += f[j]; s2 += f[j] * f[j]; }
            }
            s1 += __shfl_xor(s1, 1); s1 += __shfl_xor(s1, 2);
            s2 += __shfl_xor(s2, 1); s2 += __shfl_xor(s2, 2);
            if (p == 0) {
                float m = s1 * (1.f / 96.f);
                float var = s2 * (1.f / 96.f) - m * m;
                mrf[(s * 16 + tl) * 2] = m;
                mrf[(s * 16 + tl) * 2 + 1] = rsqrtf(var + 1e-5f);
            }
        }
    }
    __syncthreads();
    // P1: build LN'd bf16 operands (both streams)
    #pragma unroll
    for (int u = 0; u < 6; ++u) {
        int idx = lane + 64 * u;           // 0..383
        int s = idx / 192, rem = idx % 192;
        int tl = rem / 12, c8 = rem % 12;
        uint4 v = *(const uint4*)((s ? Xb : Xf) + (g0 + mbase + tl) * 96 + c8 * 8);
        float m = mrf[(s * 16 + tl) * 2], r = mrf[(s * 16 + tl) * 2 + 1];
        float f[8]; unpack8(v, f);
        #pragma unroll
        for (int j = 0; j < 8; ++j) f[j] = (f[j] - m) * r;
        *(uint4*)&xbf[s][(mbase + tl) * 104 + c8 * 8] = pack8(f);
    }
    __syncthreads();

    int l15 = lane & 15, kb = lane >> 4;
    int win_l = lane >> 5, hd = (lane >> 3) & 3, q8 = lane & 7;
    int tq = mbase + win_l * 8 + q8, ko = hd * 24;

    #pragma unroll
    for (int dir = 0; dir < 2; ++dir) {
        const ushort_t* W = dir ? wb : wf;
        const float* bs = dir ? bsb : bsf;
        ushort_t* X = dir ? Xb : Xf;

        gemm_qkv(xbf[dir],     W,        bs,       qs, mbase, l15, kb);   // Q
        gemm_qkv(xbf[dir ^ 1], W + 9216, bs + 96,  kv, mbase, l15, kb);   // K

        // scores (probs stay in regs)
        float sc[8], inv;
        {
            float qf[24];
            bf24_load(&qs[tq * 104 + ko], qf);
            float mx = -1e30f;
            #pragma unroll
            for (int j = 0; j < 8; ++j) {
                float kf[24];
                bf24_load(&kv[(mbase + win_l * 8 + j) * 104 + ko], kf);
                float s = 0.f;
                #pragma unroll
                for (int d = 0; d < 24; ++d) s += qf[d] * kf[d];
                sc[j] = s; mx = fmaxf(mx, s);
            }
            float sum = 0.f;
            #pragma unroll
            for (int j = 0; j < 8; ++j) { sc[j] = __expf(sc[j] - mx); sum += sc[j]; }
            inv = 1.f / sum;
        }

        gemm_qkv(xbf[dir ^ 1], W + 18432, bs + 192, kv, mbase, l15, kb);  // V (overwrites K)

        // O = P·V  -> qs (overwrites Q)
        {
            float of[24];
            #pragma unroll
            for (int d = 0; d < 24; ++d) of[d] = 0.f;
            #pragma unroll
            for (int j = 0; j < 8; ++j) {
                float vf[24];
                bf24_load(&kv[(mbase + win_l * 8 + j) * 104 + ko], vf);
                #pragma unroll
                for (int d = 0; d < 24; ++d) of[d] += sc[j] * vf[d];
            }
            uint4* od = (uint4*)&qs[tq * 104 + ko];
            #pragma unroll
            for (int u = 0; u < 3; ++u) {
                float f[8];
                #pragma unroll
                for (int j = 0; j < 8; ++j) f[j] = of[u * 8 + j] * inv;
                od[u] = pack8(f);
            }
        }

        // out-proj -> stage bf16 into qs -> vectorized residual RMW on X
        {
            const int abase = (mbase + l15) * 104 + kb * 8;
            short8 a0 = *(const short8*)&qs[abase];
            short8 a1 = *(const short8*)&qs[abase + 32];
            short8 a2 = *(const short8*)&qs[abase + 64];
            const ushort_t* Wo = W + 27648;
            const float* bo = bs + 288;
            #pragma unroll
            for (int t = 0; t < 6; ++t) {
                int c = t * 16 + l15;
                float bv = bo[c];
                f32x4 acc = {bv, bv, bv, bv};
                acc = MFMA16(a0, *(const short8*)&Wo[c * 96 + kb * 8], acc, 0, 0, 0);
                acc = MFMA16(a1, *(const short8*)&Wo[c * 96 + 32 + kb * 8], acc, 0, 0, 0);
                acc = MFMA16(a2, *(const short8*)&Wo[c * 96 + 64 + kb * 8], acc, 0, 0, 0);
                #pragma unroll
                for (int i = 0; i < 4; ++i)
                    qs[(mbase + kb * 4 + i) * 104 + c] = (ushort_t)f2bfbits(acc[i]);
            }
            #pragma unroll
            for (int u = 0; u < 3; ++u) {
                int idx = lane + 64 * u;       // 0..191 = 16 rows x 12
                int row = idx / 12, c8 = idx % 12;
                ushort_t* px = X + (g0 + mbase + row) * 96 + c8 * 8;
                float xf_[8], af[8];
                unpack8(*(const uint4*)px, xf_);
                unpack8(*(const uint4*)&qs[(mbase + row) * 104 + c8 * 8], af);
                float o[8];
                #pragma unroll
                for (int j = 0; j < 8; ++j) o[j] = xf_[j] + af[j];
                *(uint4*)px = pack8(o);
            }
        }
    }
}

// ---------------------------------------------------------------------------
// K3: fused LN->FFN->residual->conv. 64 tokens/block, one stream. grid 6912.
// Wave-local; LDS 39.9 KB -> 4 blocks/CU.
__global__ __launch_bounds__(256) void k_ffn(
    ushort_t* __restrict__ Xf, ushort_t* __restrict__ Xb,
    const ushort_t* __restrict__ wf, const ushort_t* __restrict__ wb,
    const float* __restrict__ bsf, const float* __restrict__ bsb)
{
    __shared__ ushort_t xb_[64 * 104];   // LN'd operand, later y (conv input)
    __shared__ ushort_t xh[64 * 104];    // raw x1 (residual base)
    __shared__ ushort_t H[64 * 104];     // hidden chunk, later conv out
    int blk = blockIdx.x, tid = threadIdx.x;
    ushort_t* X; const ushort_t* W; const float* bs;
    if (blk < 3456) { X = Xf; W = wf; bs = bsf; }
    else            { X = Xb; W = wb; bs = bsb; blk -= 3456; }
    long g0 = (long)blk * 64;
    int lane = tid & 63, wv = tid >> 6, mbase = wv * 16;
    float* mrf = (float*)&H[mbase * 104];

    {   // P0: stats
        int tl = lane >> 2, p = lane & 3;
        const ushort_t* px = X + (g0 + mbase + tl) * 96 + p * 24;
        float s1 = 0.f, s2 = 0.f;
        #pragma unroll
        for (int u = 0; u < 3; ++u) {
            float f[8]; unpack8(((const uint4*)px)[u], f);
            #pragma unroll
            for (int j = 0; j < 8; ++j) { s1 += f[j]; s2 += f[j] * f[j]; }
        }
        s1 += __shfl_xor(s1, 1); s1 += __shfl_xor(s1, 2);
        s2 += __shfl_xor(s2, 1); s2 += __shfl_xor(s2, 2);
        if (p == 0) {
            float m = s1 * (1.f / 96.f);
            float var = s2 * (1.f / 96.f) - m * m;
            mrf[tl * 2] = m; mrf[tl * 2 + 1] = rsqrtf(var + 1e-5f);
        }
    }
    __syncthreads();
    #pragma unroll
    for (int u = 0; u < 3; ++u) {   // P1: xh copy + LN'd xb_
        int idx = lane + 64 * u;    // 0..191
        int tl = idx / 12, c8 = idx % 12;
        uint4 v = *(const uint4*)(X + (g0 + mbase + tl) * 96 + c8 * 8);
        *(uint4*)&xh[(mbase + tl) * 104 + c8 * 8] = v;
        float m = mrf[tl * 2], r = mrf[tl * 2 + 1];
        float f[8]; unpack8(v, f);
        #pragma unroll
        for (int j = 0; j < 8; ++j) f[j] = (f[j] - m) * r;
        *(uint4*)&xb_[(mbase + tl) * 104 + c8 * 8] = pack8(f);
    }
    __syncthreads();
    // P2: wave-local FFN + conv
    int l15 = lane & 15, kb = lane >> 4;
    const int abase = (mbase + l15) * 104 + kb * 8;
    short8 a0 = *(const short8*)&xb_[abase];
    short8 a1 = *(const short8*)&xb_[abase + 32];
    short8 a2 = *(const short8*)&xb_[abase + 64];
    const ushort_t* W1 = W + 36864;
    const ushort_t* W2 = W + 73728;
    const ushort_t* Wc = W + 110592;
    const float* b1 = bs + 384;
    const float* b2 = bs + 768;

    f32x4 acc2[6];
    #pragma unroll
    for (int t = 0; t < 6; ++t) {
        float bb = b2[t * 16 + l15];
        acc2[t] = {bb, bb, bb, bb};
    }
    for (int ch = 0; ch < 4; ++ch) {
        #pragma unroll
        for (int t = 0; t < 6; ++t) {
            int c = ch * 96 + t * 16 + l15;
            float bb = b1[c];
            f32x4 acc = {bb, bb, bb, bb};
            acc = MFMA16(a0, *(const short8*)&W1[c * 96 + kb * 8], acc, 0, 0, 0);
            acc = MFMA16(a1, *(const short8*)&W1[c * 96 + 32 + kb * 8], acc, 0, 0, 0);
            acc = MFMA16(a2, *(const short8*)&W1[c * 96 + 64 + kb * 8], acc, 0, 0, 0);
            #pragma unroll
            for (int i = 0; i < 4; ++i)
                H[(mbase + kb * 4 + i) * 104 + t * 16 + l15] =
                    (ushort_t)f2bfbits(gelu_tanh(acc[i]));
        }
        short8 h0 = *(const short8*)&H[abase];
        short8 h1 = *(const short8*)&H[abase + 32];
        short8 h2 = *(const short8*)&H[abase + 64];
        #pragma unroll
        for (int t = 0; t < 6; ++t) {
            int c = t * 16 + l15;
            const ushort_t* w2r = &W2[c * 384 + ch * 96];
            acc2[t] = MFMA16(h0, *(const short8*)&w2r[kb * 8], acc2[t], 0, 0, 0);
            acc2[t] = MFMA16(h1, *(const short8*)&w2r[32 + kb * 8], acc2[t], 0, 0, 0);
            acc2[t] = MFMA16(h2, *(const short8*)&w2r[64 + kb * 8], acc2[t], 0, 0, 0);
        }
    }
    // residual y = x1 + ffn -> xb_ (conv input)
    #pragma unroll
    for (int t = 0; t < 6; ++t) {
        #pragma unroll
        for (int i = 0; i < 4; ++i) {
            int row = mbase + kb * 4 + i, col = t * 16 + l15;
            float y = acc2[t][i] + bf2f(xh[row * 104 + col]);
            xb_[row * 104 + col] = (ushort_t)f2bfbits(y);
        }
    }
    // conv (bias cancels in InstanceNorm) -> stage into H -> vector store
    short8 c0 = *(const short8*)&xb_[abase];
    short8 c1 = *(const short8*)&xb_[abase + 32];
    short8 c2 = *(const short8*)&xb_[abase + 64];
    #pragma unroll
    for (int t = 0; t < 6; ++t) {
        int c = t * 16 + l15;
        f32x4 acc = {0.f, 0.f, 0.f, 0.f};
        acc = MFMA16(c0, *(const short8*)&Wc[c * 96 + kb * 8], acc, 0, 0, 0);
        acc = MFMA16(c1, *(const short8*)&Wc[c * 96 + 32 + kb * 8], acc, 0, 0, 0);
        acc = MFMA16(c2, *(const short8*)&Wc[c * 96 + 64 + kb * 8], acc, 0, 0, 0);
        #pragma unroll
        for (int i = 0; i < 4; ++i)
            H[(mbase + kb * 4 + i) * 104 + c] = (ushort_t)f2bfbits(acc[i]);
    }
    #pragma unroll
    for (int u = 0; u < 3; ++u) {
        int idx = lane + 64 * u;
        int row = idx / 12, c8 = idx % 12;
        *(uint4*)(X + (g0 + mbase + row) * 96 + c8 * 8) =
            *(const uint4*)&H[(mbase + row) * 104 + c8 * 8];
    }
}

// ---------------------------------------------------------------------------
// K5: InstanceNorm partial sums (bf16 X). grid 216, block 384.
__global__ __launch_bounds__(384) void k_instats(
    const ushort_t* __restrict__ Xf, const ushort_t* __restrict__ Xb,
    float* __restrict__ partial)
{
    __shared__ float red[768];
    int blk = blockIdx.x;
    const ushort_t* X = (blk < 108) ? Xf : Xb;
    int rem = blk % 108;
    int b = rem / 54, chunk = rem % 54;
    int tid = threadIdx.x;
    int c = tid % 96, slot = tid / 96;
    long base = (long)b * TOK_PER_B + chunk * 2048;
    float s = 0.f, ss = 0.f;
    for (int i = 0; i < 512; ++i) {
        float v = bf2f(X[(base + i * 4 + slot) * 96 + c]);
        s += v; ss += v * v;
    }
    red[tid] = s; red[384 + tid] = ss;
    __syncthreads();
    if (tid < 96) {
        float S  = red[tid] + red[96 + tid] + red[192 + tid] + red[288 + tid];
        float SS = red[384 + tid] + red[480 + tid] + red[576 + tid] + red[672 + tid];
        partial[((long)blockIdx.x * 96 + tid) * 2]     = S;
        partial[((long)blockIdx.x * 96 + tid) * 2 + 1] = SS;
    }
}

__global__ __launch_bounds__(384) void k_infin(
    const float* __restrict__ partial, float* __restrict__ inMR)
{
    int tid = threadIdx.x;
    int s = tid / 192, rem = tid % 192, b = rem / 96, c = rem % 96;
    float S = 0.f, SS = 0.f;
    for (int ch = 0; ch < 54; ++ch) {
        int blk = s * 108 + b * 54 + ch;
        S  += partial[(blk * 96 + c) * 2];
        SS += partial[(blk * 96 + c) * 2 + 1];
    }
    float m = S * (1.f / 110592.f);
    float var = SS * (1.f / 110592.f) - m * m;
    inMR[tid * 2] = m;
    inMR[tid * 2 + 1] = rsqrtf(var + 1e-5f);
}

// ---------------------------------------------------------------------------
// K7: IN affine + GELU + window-reverse scatter (bf16 X -> f32 out). grid 2304.
__global__ __launch_bounds__(256) void k_scatter(
    const ushort_t* __restrict__ Xf, const ushort_t* __restrict__ Xb,
    const float* __restrict__ inMR,
    const float* __restrict__ iwf, const float* __restrict__ ibf,
    const float* __restrict__ iwb, const float* __restrict__ ibb,
    float* __restrict__ out)
{
    __shared__ float tile[192 * 97];
    int blk = blockIdx.x, s = 0;
    const ushort_t* X = Xf; const float* iw = iwf; const float* ib = ibf;
    if (blk >= 1152) { s = 1; X = Xb; iw = iwb; ib = ibb; blk -= 1152; }
    int b = blk / 576, rem = blk % 576, dw = rem / 24, hw = rem % 24;
    int tid = threadIdx.x;
    long base = ((((long)b * 24 + dw) * 24 + hw) * 24) * 8;
    for (int i = tid; i < 192 * 12; i += 256) {
        int t = i / 12, c8 = i % 12;
        float f[8]; unpack8(*(const uint4*)&X[(base + t) * 96 + c8 * 8], f);
        #pragma unroll
        for (int j = 0; j < 8; ++j) tile[t * 97 + c8 * 8 + j] = f[j];
    }
    __syncthreads();
    float* o = out + (long)s * STREAM_ELEMS;
    for (int i = tid; i < 384 * 48; i += 256) {
        int r = i / 48, w = i % 48;
        int c = r >> 2, d_off = (r >> 1) & 1, h_off = r & 1;
        int t = (w >> 1) * 8 + d_off * 4 + h_off * 2 + (w & 1);
        float v = tile[t * 97 + c];
        float m  = inMR[((s * 2 + b) * 96 + c) * 2];
        float rr = inMR[((s * 2 + b) * 96 + c) * 2 + 1];
        v = (v - m) * rr * iw[c] + ib[c];
        o[((((long)b * 96 + c) * 48 + dw * 2 + d_off) * 48 + hw * 2 + h_off) * 48 + w] = gelu_erf(v);
    }
}

// ---------------------------------------------------------------------------
extern "C" void kernel_launch(void* const* d_in, const int* in_sizes, int n_in,
                              void* d_out, int out_size, void* d_ws, size_t ws_size,
                              hipStream_t stream)
{
    #define IN(i) ((const float*)d_in[i])
    ushort_t* Xf = (ushort_t*)d_ws;
    ushort_t* Xb = Xf + (long)STREAM_ELEMS;
    ushort_t* wW  = Xb + (long)STREAM_ELEMS;
    ushort_t* wWb = wW + 119808;
    float* bsf = (float*)(wWb + 119808);
    float* bsb = bsf + 864;
    float* partial = bsb + 864;
    float* inMR = partial + 41472;

    k_fold<<<1, 256, 0, stream>>>(IN(6), IN(7), IN(8), IN(9), IN(12), IN(13), IN(14), IN(15), IN(16),
                                  IN(2), IN(3), IN(22), IN(23), IN(10), IN(11), wW, bsf);
    k_fold<<<1, 256, 0, stream>>>(IN(24), IN(25), IN(26), IN(27), IN(30), IN(31), IN(32), IN(33), IN(34),
                                  IN(20), IN(21), IN(4), IN(5), IN(28), IN(29), wWb, bsb);

    k_gather<<<2304, 256, 0, stream>>>(IN(0), IN(1), Xf, Xb);

    k_attn<<<3456, 256, 0, stream>>>(Xf, Xb, wW, wWb, bsf, bsb);

    k_ffn<<<6912, 256, 0, stream>>>(Xf, Xb, wW, wWb, bsf, bsb);

    k_instats<<<216, 384, 0, stream>>>(Xf, Xb, partial);
    k_infin<<<1, 384, 0, stream>>>(partial, inMR);

    k_scatter<<<2304, 256, 0, stream>>>(Xf, Xb, inMR,
                                        IN(18), IN(19), IN(36), IN(37),
                                        (float*)d_out);
    #undef IN
}